// Round 1
// baseline (268.227 us; speedup 1.0000x reference)
//
#include <hip/hip_runtime.h>

// GCN layer: out = relu( (D^-1/2 A D^-1/2 x) @ W + b )
// N=50000 nodes, E=800000 edges, C=64 channels, all fp32.

#define C_CH 64

// ---- Stage 1: in-degree of target (col) nodes -------------------------------
__global__ void deg_kernel(const int* __restrict__ col, float* __restrict__ deg, int E) {
    int e = blockIdx.x * blockDim.x + threadIdx.x;
    if (e < E) atomicAdd(&deg[col[e]], 1.0f);
}

// ---- Stage 2: deg -> deg^-1/2 in place --------------------------------------
__global__ void dis_kernel(float* __restrict__ deg, int N) {
    int n = blockIdx.x * blockDim.x + threadIdx.x;
    if (n < N) {
        float d = deg[n];
        deg[n] = (d > 0.0f) ? 1.0f / sqrtf(d + 1e-16f) : 0.0f;
    }
}

// ---- Stage 3+4: gather x[row], scale by norm, scatter-add into agg (= d_out) -
// One thread per (edge, channel). 64 consecutive threads share one edge, so
// row/col loads broadcast from cache and the x gather is coalesced per edge.
__global__ void scatter_kernel(const float* __restrict__ x,
                               const int* __restrict__ row,
                               const int* __restrict__ col,
                               const float* __restrict__ dis,
                               float* __restrict__ agg, int E) {
    long long idx = (long long)blockIdx.x * blockDim.x + threadIdx.x;
    int e = (int)(idx >> 6);
    int c = (int)(idx & 63);
    if (e >= E) return;
    int r = row[e];
    int t = col[e];
    float norm = dis[r] * dis[t];
    atomicAdd(&agg[(long long)t * C_CH + c], norm * x[(long long)r * C_CH + c]);
}

// ---- Stage 5+6: out = relu(agg @ W + b), in place over d_out ----------------
// Block = 256 threads = 4 nodes x 64 output channels. W (16 KB) + b staged in
// LDS; each block stages its 4 agg rows in LDS before overwriting them, so the
// in-place update is race-free (each row only touched by its own block).
__global__ void linear_kernel(float* __restrict__ io,
                              const float* __restrict__ W,
                              const float* __restrict__ b, int N) {
    __shared__ float Ws[C_CH * C_CH];
    __shared__ float bs[C_CH];
    __shared__ float ags[4][C_CH];

    int tid = threadIdx.x;
    for (int i = tid; i < C_CH * C_CH; i += 256) Ws[i] = W[i];
    if (tid < C_CH) bs[tid] = b[tid];

    int n0 = blockIdx.x * 4;
    int nl = tid >> 6;        // local node 0..3
    int oc = tid & 63;        // output channel
    int n = n0 + nl;

    if (n < N) ags[nl][oc] = io[(long long)n * C_CH + oc];
    __syncthreads();

    if (n < N) {
        float acc = bs[oc];
        #pragma unroll
        for (int k = 0; k < C_CH; ++k)
            acc = fmaf(ags[nl][k], Ws[k * C_CH + oc], acc);   // ags broadcast; Ws 2-way (free)
        io[(long long)n * C_CH + oc] = fmaxf(acc, 0.0f);
    }
}

extern "C" void kernel_launch(void* const* d_in, const int* in_sizes, int n_in,
                              void* d_out, int out_size, void* d_ws, size_t ws_size,
                              hipStream_t stream) {
    const float* x  = (const float*)d_in[0];
    const int*   ei = (const int*)  d_in[1];
    const float* W  = (const float*)d_in[2];
    const float* b  = (const float*)d_in[3];
    float* out = (float*)d_out;

    const int N = in_sizes[0] / C_CH;
    const int E = in_sizes[1] / 2;
    const int* row = ei;        // edge_index[0]
    const int* col = ei + E;    // edge_index[1]

    float* deg = (float*)d_ws;  // N floats of scratch

    // Zero the accumulators every call (harness poisons once, never re-poisons).
    hipMemsetAsync(deg, 0, (size_t)N * sizeof(float), stream);
    hipMemsetAsync(out, 0, (size_t)N * C_CH * sizeof(float), stream);

    deg_kernel<<<(E + 255) / 256, 256, 0, stream>>>(col, deg, E);
    dis_kernel<<<(N + 255) / 256, 256, 0, stream>>>(deg, N);

    long long scatter_threads = (long long)E * C_CH;
    int scatter_blocks = (int)((scatter_threads + 255) / 256);
    scatter_kernel<<<scatter_blocks, 256, 0, stream>>>(x, row, col, deg, out, E);

    linear_kernel<<<(N + 3) / 4, 256, 0, stream>>>(out, W, b, N);
}

// Round 2
// 180.975 us; speedup vs baseline: 1.4821x; 1.4821x over previous
//
#include <hip/hip_runtime.h>

// GCN layer: out = relu( (D^-1/2 A D^-1/2 x) @ W + b )
// N=50000 nodes, E=800000 edges, C=64 channels, all fp32.
//
// Strategy: build CSR (edges grouped by target node) on-device each call,
// then one wave per target node gathers+accumulates its messages with NO
// float atomics, applies the 64x64 linear from LDS, writes d_out once.

#define C_CH 64

// ---- Stage 1a: integer in-degree of target (col) nodes ----------------------
__global__ void count_kernel(const int* __restrict__ col, int* __restrict__ degi, int E) {
    int e = blockIdx.x * blockDim.x + threadIdx.x;
    if (e < E) atomicAdd(&degi[col[e]], 1);
}

// ---- Stage 1b: per-block sums of degi (scan level 1) ------------------------
__global__ void blocksum_kernel(const int* __restrict__ degi, int* __restrict__ bsum, int N) {
    __shared__ int s[256];
    int tid = threadIdx.x;
    int i = blockIdx.x * 256 + tid;
    s[tid] = (i < N) ? degi[i] : 0;
    __syncthreads();
    for (int off = 128; off > 0; off >>= 1) {
        if (tid < off) s[tid] += s[tid + off];
        __syncthreads();
    }
    if (tid == 0) bsum[blockIdx.x] = s[0];
}

// ---- Stage 1c: exclusive scan of block sums (single block, NB<=256) ---------
__global__ void scansum_kernel(const int* __restrict__ bsum, int* __restrict__ boff, int NB) {
    __shared__ int s[256];
    int tid = threadIdx.x;
    int v = (tid < NB) ? bsum[tid] : 0;
    s[tid] = v;
    __syncthreads();
    for (int off = 1; off < 256; off <<= 1) {
        int t = (tid >= off) ? s[tid - off] : 0;
        __syncthreads();
        s[tid] += t;
        __syncthreads();
    }
    if (tid < NB) boff[tid] = s[tid] - v;   // exclusive
}

// ---- Stage 1d: final scan -> row_ptr, cursor, dis = deg^-1/2 ----------------
__global__ void scanfinal_kernel(const int* __restrict__ degi, const int* __restrict__ boff,
                                 int* __restrict__ row_ptr, int* __restrict__ cursor,
                                 float* __restrict__ dis, int N) {
    __shared__ int s[256];
    int tid = threadIdx.x;
    int i = blockIdx.x * 256 + tid;
    int d = (i < N) ? degi[i] : 0;
    s[tid] = d;
    __syncthreads();
    for (int off = 1; off < 256; off <<= 1) {
        int t = (tid >= off) ? s[tid - off] : 0;
        __syncthreads();
        s[tid] += t;
        __syncthreads();
    }
    int incl = s[tid];
    int base = boff[blockIdx.x];
    if (i < N) {
        int excl = base + incl - d;
        row_ptr[i] = excl;
        cursor[i]  = excl;
        dis[i] = (d > 0) ? 1.0f / sqrtf((float)d) : 0.0f;
        if (i == N - 1) row_ptr[N] = base + incl;   // == E
    }
}

// ---- Stage 1e: bucket placement — srcs[pos] = source node of each edge ------
__global__ void place_kernel(const int* __restrict__ row, const int* __restrict__ col,
                             int* __restrict__ cursor, int* __restrict__ srcs, int E) {
    int e = blockIdx.x * blockDim.x + threadIdx.x;
    if (e < E) {
        int t = col[e];
        int pos = atomicAdd(&cursor[t], 1);
        srcs[pos] = row[e];
    }
}

// ---- Stages 3-6 fused: gather + scale + aggregate + linear + ReLU -----------
// One 64-lane wave per target node; lane = channel. 4 waves (4 nodes) / block.
// Edge list for a node is read as coalesced 64-wide chunks, then broadcast to
// the wave via __shfl. No atomics; agg row stays in registers; W in LDS.
__global__ void __launch_bounds__(256)
gather_linear_kernel(const float* __restrict__ x,
                     const int* __restrict__ srcs,
                     const int* __restrict__ row_ptr,
                     const float* __restrict__ dis,
                     const float* __restrict__ W,
                     const float* __restrict__ b,
                     float* __restrict__ out, int N) {
    __shared__ float Ws[C_CH * C_CH];
    __shared__ float bs[C_CH];
    __shared__ float ags[4][C_CH];

    int tid = threadIdx.x;
    for (int i = tid; i < C_CH * C_CH; i += 256) Ws[i] = W[i];
    if (tid < C_CH) bs[tid] = b[tid];

    int wid  = tid >> 6;       // wave id = local node 0..3
    int lane = tid & 63;       // channel
    int t = blockIdx.x * 4 + wid;

    float acc = 0.0f;
    if (t < N) {
        int start = row_ptr[t];
        int end   = row_ptr[t + 1];
        float dt  = dis[t];
        for (int base = start; base < end; base += 64) {
            int cnt = end - base; if (cnt > 64) cnt = 64;
            int   r  = (lane < cnt) ? srcs[base + lane] : 0;   // coalesced chunk
            float nr = (lane < cnt) ? dis[r] : 0.0f;           // per-lane gather (L2-resident)
            for (int j = 0; j < cnt; ++j) {
                int   rj = __shfl(r, j);
                float nj = __shfl(nr, j);
                acc = fmaf(nj, x[(long long)rj * C_CH + lane], acc);  // coalesced 256B/edge
            }
        }
        acc *= dt;
    }
    ags[wid][lane] = acc;
    __syncthreads();

    if (t < N) {
        float o = bs[lane];
        #pragma unroll
        for (int k = 0; k < C_CH; ++k)
            o = fmaf(ags[wid][k], Ws[k * C_CH + lane], o);  // ags broadcast; Ws stride-1
        out[(long long)t * C_CH + lane] = fmaxf(o, 0.0f);
    }
}

extern "C" void kernel_launch(void* const* d_in, const int* in_sizes, int n_in,
                              void* d_out, int out_size, void* d_ws, size_t ws_size,
                              hipStream_t stream) {
    const float* x  = (const float*)d_in[0];
    const int*   ei = (const int*)  d_in[1];
    const float* W  = (const float*)d_in[2];
    const float* b  = (const float*)d_in[3];
    float* out = (float*)d_out;

    const int N = in_sizes[0] / C_CH;
    const int E = in_sizes[1] / 2;
    const int* row = ei;        // edge_index[0]
    const int* col = ei + E;    // edge_index[1]

    // Workspace layout (4B elems): degi[N] | row_ptr[N+1] | cursor[N] | dis[N] | srcs[E]
    char* ws = (char*)d_ws;
    int*   degi    = (int*)ws;                       ws += (size_t)N * 4;
    int*   row_ptr = (int*)ws;                       ws += (size_t)(N + 1) * 4;
    int*   cursor  = (int*)ws;                       ws += (size_t)N * 4;
    float* dis     = (float*)ws;                     ws += (size_t)N * 4;
    int*   srcs    = (int*)ws;

    const int NB = (N + 255) / 256;   // scan blocks (196 <= 256)
    // boff reuses degi? no — need degi during final scan. Put boff after srcs.
    int* bsum = srcs + E;             // NB ints
    int* boff = bsum + NB;            // NB ints

    hipMemsetAsync(degi, 0, (size_t)N * sizeof(int), stream);

    int eb = (E + 255) / 256;
    count_kernel   <<<eb, 256, 0, stream>>>(col, degi, E);
    blocksum_kernel<<<NB, 256, 0, stream>>>(degi, bsum, N);
    scansum_kernel <<<1,  256, 0, stream>>>(bsum, boff, NB);
    scanfinal_kernel<<<NB, 256, 0, stream>>>(degi, boff, row_ptr, cursor, dis, N);
    place_kernel   <<<eb, 256, 0, stream>>>(row, col, cursor, srcs, E);

    gather_linear_kernel<<<(N + 3) / 4, 256, 0, stream>>>(x, srcs, row_ptr, dis, W, b, out, N);
}